// Round 3
// baseline (2361.807 us; speedup 1.0000x reference)
//
#include <hip/hip_runtime.h>
#include <math.h>

#define NN   262144      // nodes
#define CIN  200         // input channels
#define HIDN 64
#define EE   2097152     // edges
#define NCLS 16
#define EPSV 1e-5f

__device__ __forceinline__ float lane_bcast(float v, int l) {
    return __int_as_float(__builtin_amdgcn_readlane(__float_as_int(v), l));
}

// ---------------- stem GEMM: t = x @ W + b   ([N,200] @ [200,64]) --------------
__global__ __launch_bounds__(256) void stem_gemm(
    const float* __restrict__ x, const float* __restrict__ W,
    const float* __restrict__ bias, float* __restrict__ t)
{
    __shared__ float sA[40][64];   // sA[k][row]  (x^T chunk)
    __shared__ float sB[40][64];   // sB[k][col]
    const int tid = threadIdx.x;
    const int rid = tid >> 4;      // 0..15 -> rows rid*4..+3
    const int cid = tid & 15;      // 0..15 -> cols cid*4..+3
    const int row0 = blockIdx.x * 64;

    float acc[4][4];
#pragma unroll
    for (int i = 0; i < 4; ++i)
#pragma unroll
        for (int j = 0; j < 4; ++j) acc[i][j] = 0.f;

    for (int k0 = 0; k0 < CIN; k0 += 40) {
        __syncthreads();
        for (int idx = tid; idx < 64 * 40; idx += 256) {
            int r = idx / 40, kk = idx % 40;
            sA[kk][r] = x[(size_t)(row0 + r) * CIN + k0 + kk];
        }
        for (int idx = tid; idx < 40 * 64; idx += 256) {
            int kk = idx >> 6, c = idx & 63;
            sB[kk][c] = W[(k0 + kk) * 64 + c];
        }
        __syncthreads();
#pragma unroll
        for (int kk = 0; kk < 40; ++kk) {
            const float4 a4 = *(const float4*)&sA[kk][rid * 4];
            const float4 b4 = *(const float4*)&sB[kk][cid * 4];
            acc[0][0] = fmaf(a4.x, b4.x, acc[0][0]);
            acc[0][1] = fmaf(a4.x, b4.y, acc[0][1]);
            acc[0][2] = fmaf(a4.x, b4.z, acc[0][2]);
            acc[0][3] = fmaf(a4.x, b4.w, acc[0][3]);
            acc[1][0] = fmaf(a4.y, b4.x, acc[1][0]);
            acc[1][1] = fmaf(a4.y, b4.y, acc[1][1]);
            acc[1][2] = fmaf(a4.y, b4.z, acc[1][2]);
            acc[1][3] = fmaf(a4.y, b4.w, acc[1][3]);
            acc[2][0] = fmaf(a4.z, b4.x, acc[2][0]);
            acc[2][1] = fmaf(a4.z, b4.y, acc[2][1]);
            acc[2][2] = fmaf(a4.z, b4.z, acc[2][2]);
            acc[2][3] = fmaf(a4.z, b4.w, acc[2][3]);
            acc[3][0] = fmaf(a4.w, b4.x, acc[3][0]);
            acc[3][1] = fmaf(a4.w, b4.y, acc[3][1]);
            acc[3][2] = fmaf(a4.w, b4.z, acc[3][2]);
            acc[3][3] = fmaf(a4.w, b4.w, acc[3][3]);
        }
    }
    const float4 bb = *(const float4*)&bias[cid * 4];
#pragma unroll
    for (int i = 0; i < 4; ++i) {
        float4 o;
        o.x = acc[i][0] + bb.x;
        o.y = acc[i][1] + bb.y;
        o.z = acc[i][2] + bb.z;
        o.w = acc[i][3] + bb.w;
        *(float4*)&t[(size_t)(row0 + rid * 4 + i) * 64 + cid * 4] = o;
    }
}

// ---------------- per-channel batch stats (sum, sumsq over N rows) -------------
__global__ __launch_bounds__(256) void stats_kernel(
    const float* __restrict__ src, float* __restrict__ stats)
{
    const int c = threadIdx.x & 63;
    const int rg = threadIdx.x >> 6;   // 0..3
    float s = 0.f, s2 = 0.f;
    for (int row = blockIdx.x * 4 + rg; row < NN; row += gridDim.x * 4) {
        float v = src[(size_t)row * 64 + c];
        s += v;
        s2 += v * v;
    }
    __shared__ float ls[4][64], ls2[4][64];
    ls[rg][c] = s;
    ls2[rg][c] = s2;
    __syncthreads();
    if (threadIdx.x < 64) {
        float t1 = ls[0][c] + ls[1][c] + ls[2][c] + ls[3][c];
        float t2 = ls2[0][c] + ls2[1][c] + ls2[2][c] + ls2[3][c];
        atomicAdd(&stats[c], t1);
        atomicAdd(&stats[64 + c], t2);
    }
}

// fold BN into per-channel affine:  bn(v) = v*a + c
__global__ void finalize_bn(const float* __restrict__ stats,
                            const float* __restrict__ g, const float* __restrict__ b,
                            float* __restrict__ ac)
{
    int c = threadIdx.x;  // 0..63
    float mean = stats[c] * (1.f / NN);
    float var  = stats[64 + c] * (1.f / NN) - mean * mean;
    float rstd = rsqrtf(var + EPSV);
    float a = g[c] * rstd;
    ac[c]      = a;
    ac[64 + c] = b[c] - mean * a;
}

// ---- fused: h = affine(u) [+leaky] ; xn = LN(h) ; agg=xn ; rowv/colv = xn@W+b --
template <int RELU>
__global__ __launch_bounds__(256) void layer_pre(
    const float* __restrict__ u, const float* __restrict__ ac,
    const float* __restrict__ lng, const float* __restrict__ lnb,
    const float* __restrict__ Wr, const float* __restrict__ brv,
    const float* __restrict__ Wc, const float* __restrict__ bcv,
    float* __restrict__ agg, float* __restrict__ rowv, float* __restrict__ colv)
{
    const int lane = threadIdx.x & 63;
    const int wid  = (blockIdx.x * 256 + threadIdx.x) >> 6;
    const int nw   = (gridDim.x * 256) >> 6;

    // each lane holds column `lane` of both weight matrices
    float wr[64], wc[64];
#pragma unroll
    for (int k = 0; k < 64; ++k) {
        wr[k] = Wr[k * 64 + lane];
        wc[k] = Wc[k * 64 + lane];
    }
    const float a  = ac[lane],  c0 = ac[64 + lane];
    const float g  = lng[lane], bl = lnb[lane];
    const float br0 = brv[lane], bc0 = bcv[lane];

    for (int row = wid; row < NN; row += nw) {
        float v = u[(size_t)row * 64 + lane];
        v = v * a + c0;
        if (RELU) v = (v > 0.f) ? v : 0.01f * v;
        float s = v;
#pragma unroll
        for (int off = 32; off > 0; off >>= 1) s += __shfl_xor(s, off);
        float mean = s * (1.f / 64.f);
        float d = v - mean;
        float s2 = d * d;
#pragma unroll
        for (int off = 32; off > 0; off >>= 1) s2 += __shfl_xor(s2, off);
        float rstd = rsqrtf(s2 * (1.f / 64.f) + EPSV);
        float xn = d * rstd * g + bl;
        agg[(size_t)row * 64 + lane] = xn;

        float accr = br0, accc = bc0;
#pragma unroll
        for (int k = 0; k < 64; ++k) {
            float xk = lane_bcast(xn, k);
            accr = fmaf(xk, wr[k], accr);
            accc = fmaf(xk, wc[k], accc);
        }
        rowv[(size_t)row * 64 + lane] = accr;
        colv[(size_t)row * 64 + lane] = accc;
    }
}

// ---------------- edge gather * att -> atomic scatter-add ----------------------
__global__ __launch_bounds__(256) void edge_kernel(
    const float* __restrict__ rowv, const float* __restrict__ colv,
    const float* __restrict__ row_att, const float* __restrict__ col_att,
    const int* __restrict__ rowsrc, const int* __restrict__ rowdst,
    const int* __restrict__ colsrc, const int* __restrict__ coldst,
    float* __restrict__ agg)
{
    const int lane = threadIdx.x & 63;
    const int wid  = (blockIdx.x * 256 + threadIdx.x) >> 6;
    const int nw   = (gridDim.x * 256) >> 6;
    for (int e = wid; e < EE; e += nw) {
        int dst = rowdst[e];
        int src = rowsrc[e];
        float att = row_att[e];
        atomicAdd(&agg[(size_t)src * 64 + lane],
                  rowv[(size_t)dst * 64 + lane] * att);
        int dst2 = coldst[e];
        int src2 = colsrc[e];
        float att2 = col_att[e];
        atomicAdd(&agg[(size_t)src2 * 64 + lane],
                  colv[(size_t)dst2 * 64 + lane] * att2);
    }
}

// ------ fused output: affine+leaky -> logits = h@smW + b -> softmax ------------
__global__ __launch_bounds__(256) void out_kernel(
    const float* __restrict__ agg, const float* __restrict__ ac,
    const float* __restrict__ smW, const float* __restrict__ smb,
    float* __restrict__ out)
{
    __shared__ float sW[64 * 16];
    for (int i = threadIdx.x; i < 64 * 16; i += 256) sW[i] = smW[i];
    __syncthreads();
    const int j = threadIdx.x & 15;
    const int rloc = threadIdx.x >> 4;   // 16 rows per block
    const float bj = smb[j];
    for (int row = blockIdx.x * 16 + rloc; row < NN; row += gridDim.x * 16) {
        float acc = bj;
#pragma unroll
        for (int k = 0; k < 64; ++k) {
            float v = agg[(size_t)row * 64 + k];
            v = v * ac[k] + ac[64 + k];
            v = (v > 0.f) ? v : 0.01f * v;
            acc = fmaf(v, sW[k * 16 + j], acc);
        }
        float m = acc;
#pragma unroll
        for (int off = 8; off > 0; off >>= 1) m = fmaxf(m, __shfl_xor(m, off));
        float e = expf(acc - m);
        float ssum = e;
#pragma unroll
        for (int off = 8; off > 0; off >>= 1) ssum += __shfl_xor(ssum, off);
        out[(size_t)row * 16 + j] = e / ssum;
    }
}

// ------------------------------------------------------------------------------
extern "C" void kernel_launch(void* const* d_in, const int* in_sizes, int n_in,
                              void* d_out, int out_size, void* d_ws, size_t ws_size,
                              hipStream_t stream)
{
    const float* x        = (const float*)d_in[0];
    const float* row_att  = (const float*)d_in[1];
    const float* col_att  = (const float*)d_in[2];
    const float* prelin_W = (const float*)d_in[3];
    const float* prelin_b = (const float*)d_in[4];
    const float* bn0_g    = (const float*)d_in[5];
    const float* bn0_b    = (const float*)d_in[6];
    const float* ln_g     = (const float*)d_in[7];
    const float* ln_b     = (const float*)d_in[8];
    const float* Wrv      = (const float*)d_in[9];
    const float* brv      = (const float*)d_in[10];
    const float* Wcv      = (const float*)d_in[11];
    const float* bcv      = (const float*)d_in[12];
    const float* bn_g     = (const float*)d_in[13];
    const float* bn_b     = (const float*)d_in[14];
    const float* sm_W     = (const float*)d_in[15];
    const float* sm_b     = (const float*)d_in[16];
    const int*   rowsrc   = (const int*)d_in[17];
    const int*   rowdst   = (const int*)d_in[18];
    const int*   colsrc   = (const int*)d_in[19];
    const int*   coldst   = (const int*)d_in[20];
    float* out = (float*)d_out;

    // workspace layout (needs 4*N*64*4 B = 268.4 MB + 3 KB)
    const size_t NH = (size_t)NN * 64;
    float* ws   = (float*)d_ws;
    float* t    = ws;            // stem pre-BN output; reused as agg1
    float* agg0 = ws + NH;
    float* rowv = ws + 2 * NH;
    float* colv = ws + 3 * NH;
    float* agg1 = t;
    float* stats = ws + 4 * NH;  // 3 x 128
    float* ac    = stats + 3 * 128;  // 3 x 128 folded BN affine

    hipMemsetAsync(stats, 0, 3 * 128 * sizeof(float), stream);

    // stem
    stem_gemm<<<NN / 64, 256, 0, stream>>>(x, prelin_W, prelin_b, t);
    stats_kernel<<<1024, 256, 0, stream>>>(t, stats);
    finalize_bn<<<1, 64, 0, stream>>>(stats, bn0_g, bn0_b, ac);

    // layer 0
    layer_pre<0><<<4096, 256, 0, stream>>>(t, ac, ln_g, ln_b,
                                           Wrv, brv, Wcv, bcv,
                                           agg0, rowv, colv);
    edge_kernel<<<2048, 256, 0, stream>>>(rowv, colv, row_att, col_att,
                                          rowsrc, rowdst, colsrc, coldst, agg0);
    stats_kernel<<<1024, 256, 0, stream>>>(agg0, stats + 128);
    finalize_bn<<<1, 64, 0, stream>>>(stats + 128, bn_g, bn_b, ac + 128);

    // layer 1
    layer_pre<1><<<4096, 256, 0, stream>>>(agg0, ac + 128, ln_g + 64, ln_b + 64,
                                           Wrv + 4096, brv + 64, Wcv + 4096, bcv + 64,
                                           agg1, rowv, colv);
    edge_kernel<<<2048, 256, 0, stream>>>(rowv, colv, row_att, col_att,
                                          rowsrc, rowdst, colsrc, coldst, agg1);
    stats_kernel<<<1024, 256, 0, stream>>>(agg1, stats + 256);
    finalize_bn<<<1, 64, 0, stream>>>(stats + 256, bn_g + 64, bn_b + 64, ac + 256);

    // output head
    out_kernel<<<2048, 256, 0, stream>>>(agg1, ac + 256, sm_W, sm_b, out);
}

// Round 4
// 1918.274 us; speedup vs baseline: 1.2312x; 1.2312x over previous
//
#include <hip/hip_runtime.h>
#include <math.h>

#define NN   262144      // nodes
#define CIN  200         // input channels
#define EE   2097152     // edges
#define NB   (2*NN)      // flat count/ptr sections: [row | col]
#define EPSV 1e-5f

__device__ __forceinline__ float lane_bcast(float v, int l) {
    return __int_as_float(__builtin_amdgcn_readlane(__float_as_int(v), l));
}

// ---------------- stem GEMM: t = x @ W + b   ([N,200] @ [200,64]) --------------
__global__ __launch_bounds__(256) void stem_gemm(
    const float* __restrict__ x, const float* __restrict__ W,
    const float* __restrict__ bias, float* __restrict__ t)
{
    __shared__ float sA[40][64];
    __shared__ float sB[40][64];
    const int tid = threadIdx.x;
    const int rid = tid >> 4;
    const int cid = tid & 15;
    const int row0 = blockIdx.x * 64;

    float acc[4][4];
#pragma unroll
    for (int i = 0; i < 4; ++i)
#pragma unroll
        for (int j = 0; j < 4; ++j) acc[i][j] = 0.f;

    for (int k0 = 0; k0 < CIN; k0 += 40) {
        __syncthreads();
        for (int idx = tid; idx < 64 * 40; idx += 256) {
            int r = idx / 40, kk = idx % 40;
            sA[kk][r] = x[(size_t)(row0 + r) * CIN + k0 + kk];
        }
        for (int idx = tid; idx < 40 * 64; idx += 256) {
            int kk = idx >> 6, c = idx & 63;
            sB[kk][c] = W[(k0 + kk) * 64 + c];
        }
        __syncthreads();
#pragma unroll
        for (int kk = 0; kk < 40; ++kk) {
            const float4 a4 = *(const float4*)&sA[kk][rid * 4];
            const float4 b4 = *(const float4*)&sB[kk][cid * 4];
            acc[0][0] = fmaf(a4.x, b4.x, acc[0][0]);
            acc[0][1] = fmaf(a4.x, b4.y, acc[0][1]);
            acc[0][2] = fmaf(a4.x, b4.z, acc[0][2]);
            acc[0][3] = fmaf(a4.x, b4.w, acc[0][3]);
            acc[1][0] = fmaf(a4.y, b4.x, acc[1][0]);
            acc[1][1] = fmaf(a4.y, b4.y, acc[1][1]);
            acc[1][2] = fmaf(a4.y, b4.z, acc[1][2]);
            acc[1][3] = fmaf(a4.y, b4.w, acc[1][3]);
            acc[2][0] = fmaf(a4.z, b4.x, acc[2][0]);
            acc[2][1] = fmaf(a4.z, b4.y, acc[2][1]);
            acc[2][2] = fmaf(a4.z, b4.z, acc[2][2]);
            acc[2][3] = fmaf(a4.z, b4.w, acc[2][3]);
            acc[3][0] = fmaf(a4.w, b4.x, acc[3][0]);
            acc[3][1] = fmaf(a4.w, b4.y, acc[3][1]);
            acc[3][2] = fmaf(a4.w, b4.z, acc[3][2]);
            acc[3][3] = fmaf(a4.w, b4.w, acc[3][3]);
        }
    }
    const float4 bb = *(const float4*)&bias[cid * 4];
#pragma unroll
    for (int i = 0; i < 4; ++i) {
        float4 o;
        o.x = acc[i][0] + bb.x;
        o.y = acc[i][1] + bb.y;
        o.z = acc[i][2] + bb.z;
        o.w = acc[i][3] + bb.w;
        *(float4*)&t[(size_t)(row0 + rid * 4 + i) * 64 + cid * 4] = o;
    }
}

// ---------------- per-channel batch stats (stem only) --------------------------
__global__ __launch_bounds__(256) void stats_kernel(
    const float* __restrict__ src, float* __restrict__ stats)
{
    const int c = threadIdx.x & 63;
    const int rg = threadIdx.x >> 6;
    float s = 0.f, s2 = 0.f;
    for (int row = blockIdx.x * 4 + rg; row < NN; row += gridDim.x * 4) {
        float v = src[(size_t)row * 64 + c];
        s += v;
        s2 += v * v;
    }
    __shared__ float ls[4][64], ls2[4][64];
    ls[rg][c] = s;
    ls2[rg][c] = s2;
    __syncthreads();
    if (threadIdx.x < 64) {
        atomicAdd(&stats[c],      ls[0][c] + ls[1][c] + ls[2][c] + ls[3][c]);
        atomicAdd(&stats[64 + c], ls2[0][c] + ls2[1][c] + ls2[2][c] + ls2[3][c]);
    }
}

// fold BN into per-channel affine:  bn(v) = v*a + c
__global__ void finalize_bn(const float* __restrict__ stats,
                            const float* __restrict__ g, const float* __restrict__ b,
                            float* __restrict__ ac)
{
    int c = threadIdx.x;
    float mean = stats[c] * (1.f / NN);
    float var  = stats[64 + c] * (1.f / NN) - mean * mean;
    float rstd = rsqrtf(var + EPSV);
    float a = g[c] * rstd;
    ac[c]      = a;
    ac[64 + c] = b[c] - mean * a;
}

// ---- fused: h = affine(u) [+leaky] ; xn = LN(h) ; agg=xn ; rowv/colv = xn@W+b --
template <int RELU>
__global__ __launch_bounds__(256) void layer_pre(
    const float* __restrict__ u, const float* __restrict__ ac,
    const float* __restrict__ lng, const float* __restrict__ lnb,
    const float* __restrict__ Wr, const float* __restrict__ brv,
    const float* __restrict__ Wc, const float* __restrict__ bcv,
    float* __restrict__ agg, float* __restrict__ rowv, float* __restrict__ colv)
{
    const int lane = threadIdx.x & 63;
    const int wid  = (blockIdx.x * 256 + threadIdx.x) >> 6;
    const int nw   = (gridDim.x * 256) >> 6;

    float wr[64], wc[64];
#pragma unroll
    for (int k = 0; k < 64; ++k) {
        wr[k] = Wr[k * 64 + lane];
        wc[k] = Wc[k * 64 + lane];
    }
    const float a  = ac[lane],  c0 = ac[64 + lane];
    const float g  = lng[lane], bl = lnb[lane];
    const float br0 = brv[lane], bc0 = bcv[lane];

    for (int row = wid; row < NN; row += nw) {
        float v = u[(size_t)row * 64 + lane];
        v = v * a + c0;
        if (RELU) v = (v > 0.f) ? v : 0.01f * v;
        float s = v;
#pragma unroll
        for (int off = 32; off > 0; off >>= 1) s += __shfl_xor(s, off);
        float mean = s * (1.f / 64.f);
        float d = v - mean;
        float s2 = d * d;
#pragma unroll
        for (int off = 32; off > 0; off >>= 1) s2 += __shfl_xor(s2, off);
        float rstd = rsqrtf(s2 * (1.f / 64.f) + EPSV);
        float xn = d * rstd * g + bl;
        agg[(size_t)row * 64 + lane] = xn;

        float accr = br0, accc = bc0;
#pragma unroll
        for (int k = 0; k < 64; ++k) {
            float xk = lane_bcast(xn, k);
            accr = fmaf(xk, wr[k], accr);
            accc = fmaf(xk, wc[k], accc);
        }
        rowv[(size_t)row * 64 + lane] = accr;
        colv[(size_t)row * 64 + lane] = accc;
    }
}

// ================= CSR build (graph identical for both layers) ==================
// counts[0..NN)   = row-edge counts by src; counts[NN..2NN) = col-edge counts
__global__ __launch_bounds__(256) void hist_kernel(
    const int* __restrict__ rowsrc, const int* __restrict__ colsrc,
    int* __restrict__ cnt)
{
    for (int i = blockIdx.x * 256 + threadIdx.x; i < EE; i += gridDim.x * 256) {
        atomicAdd(&cnt[rowsrc[i]], 1);
        atomicAdd(&cnt[NN + colsrc[i]], 1);
    }
}

// scan1: per-block (1024 elems) sums  -> bsum[512]
__global__ __launch_bounds__(256) void scan1_kernel(
    const int* __restrict__ cnt, int* __restrict__ bsum)
{
    const int t = threadIdx.x;
    const int base = blockIdx.x * 1024 + t * 4;
    int s = cnt[base] + cnt[base + 1] + cnt[base + 2] + cnt[base + 3];
    __shared__ int sm[256];
    sm[t] = s;
    __syncthreads();
    for (int off = 1; off < 256; off <<= 1) {
        int v = (t >= off) ? sm[t - off] : 0;
        __syncthreads();
        sm[t] += v;
        __syncthreads();
    }
    if (t == 255) bsum[blockIdx.x] = sm[255];
}

// scan2: single block, exclusive scan of bsum[512] -> bpre[512]; ptr[NB]=2E
__global__ __launch_bounds__(512) void scan2_kernel(
    const int* __restrict__ bsum, int* __restrict__ bpre, int* __restrict__ ptr)
{
    const int t = threadIdx.x;   // 0..511
    __shared__ int sm[512];
    int orig = bsum[t];
    sm[t] = orig;
    __syncthreads();
    for (int off = 1; off < 512; off <<= 1) {
        int v = (t >= off) ? sm[t - off] : 0;
        __syncthreads();
        sm[t] += v;
        __syncthreads();
    }
    bpre[t] = sm[t] - orig;      // exclusive
    if (t == 0) ptr[NB] = 2 * EE;
}

// scan3: per-block exclusive scan of its 1024 chunk + block offset.
// writes ptr[] and cursor[] (same values; cursor consumed by fill's atomics)
__global__ __launch_bounds__(256) void scan3_kernel(
    const int* __restrict__ cnt, const int* __restrict__ bpre,
    int* __restrict__ ptr, int* __restrict__ cursor)
{
    const int t = threadIdx.x;
    const int base = blockIdx.x * 1024 + t * 4;
    int c0 = cnt[base], c1 = cnt[base + 1], c2 = cnt[base + 2], c3 = cnt[base + 3];
    int tsum = c0 + c1 + c2 + c3;
    __shared__ int sm[256];
    sm[t] = tsum;
    __syncthreads();
    for (int off = 1; off < 256; off <<= 1) {
        int v = (t >= off) ? sm[t - off] : 0;
        __syncthreads();
        sm[t] += v;
        __syncthreads();
    }
    int p = bpre[blockIdx.x] + sm[t] - tsum;   // exclusive prefix for this thread
    ptr[base] = p;     cursor[base] = p;     p += c0;
    ptr[base + 1] = p; cursor[base + 1] = p; p += c1;
    ptr[base + 2] = p; cursor[base + 2] = p; p += c2;
    ptr[base + 3] = p; cursor[base + 3] = p;
}

// fill: scatter (dst, att) into CSR slots
__global__ __launch_bounds__(256) void fill_kernel(
    const int* __restrict__ rowsrc, const int* __restrict__ rowdst,
    const float* __restrict__ ratt,
    const int* __restrict__ colsrc, const int* __restrict__ coldst,
    const float* __restrict__ catt,
    int* __restrict__ cursor, int* __restrict__ dstp, float* __restrict__ attp)
{
    for (int i = blockIdx.x * 256 + threadIdx.x; i < EE; i += gridDim.x * 256) {
        int p = atomicAdd(&cursor[rowsrc[i]], 1);
        dstp[p] = rowdst[i];
        attp[p] = ratt[i];
        int q = atomicAdd(&cursor[NN + colsrc[i]], 1);
        dstp[q] = coldst[i];
        attp[q] = catt[i];
    }
}

// ---- gather: agg[n] = xn[n] + sum rowv[dst]*att + sum colv[dst]*att; +stats ----
__global__ __launch_bounds__(256) void gather_kernel(
    const float* __restrict__ rowv, const float* __restrict__ colv,
    const int* __restrict__ ptr, const int* __restrict__ dstp,
    const float* __restrict__ attp,
    float* __restrict__ agg, float* __restrict__ stats)
{
    const int lane = threadIdx.x & 63;
    const int wloc = threadIdx.x >> 6;
    const int wid  = (blockIdx.x * 256 + threadIdx.x) >> 6;
    const int nw   = (gridDim.x * 256) >> 6;
    float s = 0.f, s2 = 0.f;

    for (int n = wid; n < NN; n += nw) {
        float acc = agg[(size_t)n * 64 + lane];   // xn residual
        int b0 = ptr[n], e0 = ptr[n + 1];
        for (int i = b0; i < e0; ++i) {
            int d = dstp[i];
            float a = attp[i];
            acc = fmaf(rowv[(size_t)d * 64 + lane], a, acc);
        }
        int b1 = ptr[NN + n], e1 = ptr[NN + n + 1];
        for (int i = b1; i < e1; ++i) {
            int d = dstp[i];
            float a = attp[i];
            acc = fmaf(colv[(size_t)d * 64 + lane], a, acc);
        }
        agg[(size_t)n * 64 + lane] = acc;
        s += acc;
        s2 += acc * acc;
    }
    __shared__ float ls[4][64], ls2[4][64];
    ls[wloc][lane] = s;
    ls2[wloc][lane] = s2;
    __syncthreads();
    if (threadIdx.x < 64) {
        atomicAdd(&stats[lane],      ls[0][lane] + ls[1][lane] + ls[2][lane] + ls[3][lane]);
        atomicAdd(&stats[64 + lane], ls2[0][lane] + ls2[1][lane] + ls2[2][lane] + ls2[3][lane]);
    }
}

// ------ fused output: affine+leaky -> logits = h@smW + b -> softmax ------------
__global__ __launch_bounds__(256) void out_kernel(
    const float* __restrict__ agg, const float* __restrict__ ac,
    const float* __restrict__ smW, const float* __restrict__ smb,
    float* __restrict__ out)
{
    __shared__ float sW[64 * 16];
    for (int i = threadIdx.x; i < 64 * 16; i += 256) sW[i] = smW[i];
    __syncthreads();
    const int j = threadIdx.x & 15;
    const int rloc = threadIdx.x >> 4;
    const float bj = smb[j];
    for (int row = blockIdx.x * 16 + rloc; row < NN; row += gridDim.x * 16) {
        float acc = bj;
#pragma unroll
        for (int k = 0; k < 64; ++k) {
            float v = agg[(size_t)row * 64 + k];
            v = v * ac[k] + ac[64 + k];
            v = (v > 0.f) ? v : 0.01f * v;
            acc = fmaf(v, sW[k * 16 + j], acc);
        }
        float m = acc;
#pragma unroll
        for (int off = 8; off > 0; off >>= 1) m = fmaxf(m, __shfl_xor(m, off));
        float e = expf(acc - m);
        float ssum = e;
#pragma unroll
        for (int off = 8; off > 0; off >>= 1) ssum += __shfl_xor(ssum, off);
        out[(size_t)row * 16 + j] = e / ssum;
    }
}

// ------------------------------------------------------------------------------
extern "C" void kernel_launch(void* const* d_in, const int* in_sizes, int n_in,
                              void* d_out, int out_size, void* d_ws, size_t ws_size,
                              hipStream_t stream)
{
    const float* x        = (const float*)d_in[0];
    const float* row_att  = (const float*)d_in[1];
    const float* col_att  = (const float*)d_in[2];
    const float* prelin_W = (const float*)d_in[3];
    const float* prelin_b = (const float*)d_in[4];
    const float* bn0_g    = (const float*)d_in[5];
    const float* bn0_b    = (const float*)d_in[6];
    const float* ln_g     = (const float*)d_in[7];
    const float* ln_b     = (const float*)d_in[8];
    const float* Wrv      = (const float*)d_in[9];
    const float* brv      = (const float*)d_in[10];
    const float* Wcv      = (const float*)d_in[11];
    const float* bcv      = (const float*)d_in[12];
    const float* bn_g     = (const float*)d_in[13];
    const float* bn_b     = (const float*)d_in[14];
    const float* sm_W     = (const float*)d_in[15];
    const float* sm_b     = (const float*)d_in[16];
    const int*   rowsrc   = (const int*)d_in[17];
    const int*   rowdst   = (const int*)d_in[18];
    const int*   colsrc   = (const int*)d_in[19];
    const int*   coldst   = (const int*)d_in[20];
    float* out = (float*)d_out;

    // ---- workspace layout (~306 MB) ----
    const size_t NH = (size_t)NN * 64;
    float* ws    = (float*)d_ws;
    float* t     = ws;               // stem output; reused as agg1
    float* agg0  = ws + NH;
    float* rowv  = ws + 2 * NH;
    float* colv  = ws + 3 * NH;
    float* agg1  = t;

    char* extra = (char*)(ws + 4 * NH);
    float* stats  = (float*)extra;                 extra += 3 * 128 * sizeof(float);
    float* ac     = (float*)extra;                 extra += 3 * 128 * sizeof(float);
    int*   bsum   = (int*)extra;                   extra += 512 * sizeof(int);
    int*   bpre   = (int*)extra;                   extra += 512 * sizeof(int);
    int*   ptr    = (int*)extra;                   extra += (NB + 1) * sizeof(int);
    int*   counts = (int*)extra;                   extra += NB * sizeof(int);      // also hist
    int*   cursor = (int*)extra;                   extra += NB * sizeof(int);
    int*   dstp   = (int*)extra;                   extra += 2 * (size_t)EE * sizeof(int);
    float* attp   = (float*)extra;

    hipMemsetAsync(stats, 0, 3 * 128 * sizeof(float), stream);
    hipMemsetAsync(counts, 0, NB * sizeof(int), stream);

    // ---- CSR build (used by both layers) ----
    hist_kernel<<<2048, 256, 0, stream>>>(rowsrc, colsrc, counts);
    scan1_kernel<<<512, 256, 0, stream>>>(counts, bsum);
    scan2_kernel<<<1, 512, 0, stream>>>(bsum, bpre, ptr);
    scan3_kernel<<<512, 256, 0, stream>>>(counts, bpre, ptr, cursor);
    fill_kernel<<<2048, 256, 0, stream>>>(rowsrc, rowdst, row_att,
                                          colsrc, coldst, col_att,
                                          cursor, dstp, attp);

    // ---- stem ----
    stem_gemm<<<NN / 64, 256, 0, stream>>>(x, prelin_W, prelin_b, t);
    stats_kernel<<<1024, 256, 0, stream>>>(t, stats);
    finalize_bn<<<1, 64, 0, stream>>>(stats, bn0_g, bn0_b, ac);

    // ---- layer 0 ----
    layer_pre<0><<<4096, 256, 0, stream>>>(t, ac, ln_g, ln_b,
                                           Wrv, brv, Wcv, bcv,
                                           agg0, rowv, colv);
    gather_kernel<<<8192, 256, 0, stream>>>(rowv, colv, ptr, dstp, attp,
                                            agg0, stats + 128);
    finalize_bn<<<1, 64, 0, stream>>>(stats + 128, bn_g, bn_b, ac + 128);

    // ---- layer 1 ----
    layer_pre<1><<<4096, 256, 0, stream>>>(agg0, ac + 128, ln_g + 64, ln_b + 64,
                                           Wrv + 4096, brv + 64, Wcv + 4096, bcv + 64,
                                           agg1, rowv, colv);
    gather_kernel<<<8192, 256, 0, stream>>>(rowv, colv, ptr, dstp, attp,
                                            agg1, stats + 256);
    finalize_bn<<<1, 64, 0, stream>>>(stats + 256, bn_g + 64, bn_b + 64, ac + 256);

    // ---- output head ----
    out_kernel<<<2048, 256, 0, stream>>>(agg1, ac + 256, sm_W, sm_b, out);
}

// Round 5
// 1825.632 us; speedup vs baseline: 1.2937x; 1.0507x over previous
//
#include <hip/hip_runtime.h>
#include <math.h>

#define NN   262144      // nodes
#define CIN  200         // input channels
#define EE   2097152     // edges
#define NB   (2*NN)      // flat count/ptr sections: [row | col]
#define EPSV 1e-5f

__device__ __forceinline__ float lane_bcast(float v, int l) {
    return __int_as_float(__builtin_amdgcn_readlane(__float_as_int(v), l));
}

// ---------------- stem GEMM: t = x @ W + b   ([N,200] @ [200,64]) --------------
__global__ __launch_bounds__(256) void stem_gemm(
    const float* __restrict__ x, const float* __restrict__ W,
    const float* __restrict__ bias, float* __restrict__ t)
{
    __shared__ float sA[40][64];
    __shared__ float sB[40][64];
    const int tid = threadIdx.x;
    const int rid = tid >> 4;
    const int cid = tid & 15;
    const int row0 = blockIdx.x * 64;

    float acc[4][4];
#pragma unroll
    for (int i = 0; i < 4; ++i)
#pragma unroll
        for (int j = 0; j < 4; ++j) acc[i][j] = 0.f;

    for (int k0 = 0; k0 < CIN; k0 += 40) {
        __syncthreads();
        for (int idx = tid; idx < 64 * 40; idx += 256) {
            int r = idx / 40, kk = idx % 40;
            sA[kk][r] = x[(size_t)(row0 + r) * CIN + k0 + kk];
        }
        for (int idx = tid; idx < 40 * 64; idx += 256) {
            int kk = idx >> 6, c = idx & 63;
            sB[kk][c] = W[(k0 + kk) * 64 + c];
        }
        __syncthreads();
#pragma unroll
        for (int kk = 0; kk < 40; ++kk) {
            const float4 a4 = *(const float4*)&sA[kk][rid * 4];
            const float4 b4 = *(const float4*)&sB[kk][cid * 4];
            acc[0][0] = fmaf(a4.x, b4.x, acc[0][0]);
            acc[0][1] = fmaf(a4.x, b4.y, acc[0][1]);
            acc[0][2] = fmaf(a4.x, b4.z, acc[0][2]);
            acc[0][3] = fmaf(a4.x, b4.w, acc[0][3]);
            acc[1][0] = fmaf(a4.y, b4.x, acc[1][0]);
            acc[1][1] = fmaf(a4.y, b4.y, acc[1][1]);
            acc[1][2] = fmaf(a4.y, b4.z, acc[1][2]);
            acc[1][3] = fmaf(a4.y, b4.w, acc[1][3]);
            acc[2][0] = fmaf(a4.z, b4.x, acc[2][0]);
            acc[2][1] = fmaf(a4.z, b4.y, acc[2][1]);
            acc[2][2] = fmaf(a4.z, b4.z, acc[2][2]);
            acc[2][3] = fmaf(a4.z, b4.w, acc[2][3]);
            acc[3][0] = fmaf(a4.w, b4.x, acc[3][0]);
            acc[3][1] = fmaf(a4.w, b4.y, acc[3][1]);
            acc[3][2] = fmaf(a4.w, b4.z, acc[3][2]);
            acc[3][3] = fmaf(a4.w, b4.w, acc[3][3]);
        }
    }
    const float4 bb = *(const float4*)&bias[cid * 4];
#pragma unroll
    for (int i = 0; i < 4; ++i) {
        float4 o;
        o.x = acc[i][0] + bb.x;
        o.y = acc[i][1] + bb.y;
        o.z = acc[i][2] + bb.z;
        o.w = acc[i][3] + bb.w;
        *(float4*)&t[(size_t)(row0 + rid * 4 + i) * 64 + cid * 4] = o;
    }
}

// ---------------- per-channel batch stats (stem only) --------------------------
__global__ __launch_bounds__(256) void stats_kernel(
    const float* __restrict__ src, float* __restrict__ stats)
{
    const int c = threadIdx.x & 63;
    const int rg = threadIdx.x >> 6;
    float s = 0.f, s2 = 0.f;
    for (int row = blockIdx.x * 4 + rg; row < NN; row += gridDim.x * 4) {
        float v = src[(size_t)row * 64 + c];
        s += v;
        s2 += v * v;
    }
    __shared__ float ls[4][64], ls2[4][64];
    ls[rg][c] = s;
    ls2[rg][c] = s2;
    __syncthreads();
    if (threadIdx.x < 64) {
        atomicAdd(&stats[c],      ls[0][c] + ls[1][c] + ls[2][c] + ls[3][c]);
        atomicAdd(&stats[64 + c], ls2[0][c] + ls2[1][c] + ls2[2][c] + ls2[3][c]);
    }
}

// fold BN into per-channel affine:  bn(v) = v*a + c
__global__ void finalize_bn(const float* __restrict__ stats,
                            const float* __restrict__ g, const float* __restrict__ b,
                            float* __restrict__ ac)
{
    int c = threadIdx.x;
    float mean = stats[c] * (1.f / NN);
    float var  = stats[64 + c] * (1.f / NN) - mean * mean;
    float rstd = rsqrtf(var + EPSV);
    float a = g[c] * rstd;
    ac[c]      = a;
    ac[64 + c] = b[c] - mean * a;
}

// ---- ln: xn = LN(leaky?(affine(u))) ------------------------------------------
template <int RELU>
__global__ __launch_bounds__(256) void ln_kernel(
    const float* __restrict__ u, const float* __restrict__ ac,
    const float* __restrict__ lng, const float* __restrict__ lnb,
    float* __restrict__ xn)
{
    const int lane = threadIdx.x & 63;
    const int wid  = (blockIdx.x * 256 + threadIdx.x) >> 6;
    const int nw   = (gridDim.x * 256) >> 6;
    const float a  = ac[lane],  c0 = ac[64 + lane];
    const float g  = lng[lane], bl = lnb[lane];

    for (int row = wid; row < NN; row += nw) {
        float v = u[(size_t)row * 64 + lane];
        v = v * a + c0;
        if (RELU) v = (v > 0.f) ? v : 0.01f * v;
        float s = v;
#pragma unroll
        for (int off = 32; off > 0; off >>= 1) s += __shfl_xor(s, off);
        float mean = s * (1.f / 64.f);
        float d = v - mean;
        float s2 = d * d;
#pragma unroll
        for (int off = 32; off > 0; off >>= 1) s2 += __shfl_xor(s2, off);
        float rstd = rsqrtf(s2 * (1.f / 64.f) + EPSV);
        xn[(size_t)row * 64 + lane] = d * rstd * g + bl;
    }
}

// ================= CSR build (graph identical for both layers) ==================
__global__ __launch_bounds__(256) void hist_kernel(
    const int* __restrict__ rowsrc, const int* __restrict__ colsrc,
    int* __restrict__ cnt)
{
    for (int i = blockIdx.x * 256 + threadIdx.x; i < EE; i += gridDim.x * 256) {
        atomicAdd(&cnt[rowsrc[i]], 1);
        atomicAdd(&cnt[NN + colsrc[i]], 1);
    }
}

__global__ __launch_bounds__(256) void scan1_kernel(
    const int* __restrict__ cnt, int* __restrict__ bsum)
{
    const int t = threadIdx.x;
    const int base = blockIdx.x * 1024 + t * 4;
    int s = cnt[base] + cnt[base + 1] + cnt[base + 2] + cnt[base + 3];
    __shared__ int sm[256];
    sm[t] = s;
    __syncthreads();
    for (int off = 1; off < 256; off <<= 1) {
        int v = (t >= off) ? sm[t - off] : 0;
        __syncthreads();
        sm[t] += v;
        __syncthreads();
    }
    if (t == 255) bsum[blockIdx.x] = sm[255];
}

__global__ __launch_bounds__(512) void scan2_kernel(
    const int* __restrict__ bsum, int* __restrict__ bpre, int* __restrict__ ptr)
{
    const int t = threadIdx.x;
    __shared__ int sm[512];
    int orig = bsum[t];
    sm[t] = orig;
    __syncthreads();
    for (int off = 1; off < 512; off <<= 1) {
        int v = (t >= off) ? sm[t - off] : 0;
        __syncthreads();
        sm[t] += v;
        __syncthreads();
    }
    bpre[t] = sm[t] - orig;
    if (t == 0) ptr[NB] = 2 * EE;
}

__global__ __launch_bounds__(256) void scan3_kernel(
    const int* __restrict__ cnt, const int* __restrict__ bpre,
    int* __restrict__ ptr, int* __restrict__ cursor)
{
    const int t = threadIdx.x;
    const int base = blockIdx.x * 1024 + t * 4;
    int c0 = cnt[base], c1 = cnt[base + 1], c2 = cnt[base + 2], c3 = cnt[base + 3];
    int tsum = c0 + c1 + c2 + c3;
    __shared__ int sm[256];
    sm[t] = tsum;
    __syncthreads();
    for (int off = 1; off < 256; off <<= 1) {
        int v = (t >= off) ? sm[t - off] : 0;
        __syncthreads();
        sm[t] += v;
        __syncthreads();
    }
    int p = bpre[blockIdx.x] + sm[t] - tsum;
    ptr[base] = p;     cursor[base] = p;     p += c0;
    ptr[base + 1] = p; cursor[base + 1] = p; p += c1;
    ptr[base + 2] = p; cursor[base + 2] = p; p += c2;
    ptr[base + 3] = p; cursor[base + 3] = p;
}

__global__ __launch_bounds__(256) void fill_kernel(
    const int* __restrict__ rowsrc, const int* __restrict__ rowdst,
    const float* __restrict__ ratt,
    const int* __restrict__ colsrc, const int* __restrict__ coldst,
    const float* __restrict__ catt,
    int* __restrict__ cursor, int* __restrict__ dstp, float* __restrict__ attp)
{
    for (int i = blockIdx.x * 256 + threadIdx.x; i < EE; i += gridDim.x * 256) {
        int p = atomicAdd(&cursor[rowsrc[i]], 1);
        dstp[p] = rowdst[i];
        attp[p] = ratt[i];
        int q = atomicAdd(&cursor[NN + colsrc[i]], 1);
        dstp[q] = coldst[i];
        attp[q] = catt[i];
    }
}

// ---- gather xn + fused GEMV epilogue + fused BN stats -------------------------
// out[n] = xn[n] + (Σ att·xn[dst])row @ Wr + br·Σatt_row
//                + (Σ att·xn[dst])col @ Wc + bc·Σatt_col
__global__ __launch_bounds__(256) void gather_gemv(
    const float* __restrict__ xn,
    const int* __restrict__ ptr, const int* __restrict__ dstp,
    const float* __restrict__ attp,
    const float* __restrict__ Wr, const float* __restrict__ br,
    const float* __restrict__ Wc, const float* __restrict__ bc,
    float* __restrict__ out, float* __restrict__ stats)
{
    __shared__ float sWr[64 * 64];   // 16 KB
    __shared__ float sWc[64 * 64];   // 16 KB
    for (int i = threadIdx.x; i < 64 * 64; i += 256) {
        sWr[i] = Wr[i];
        sWc[i] = Wc[i];
    }
    __syncthreads();

    const int lane = threadIdx.x & 63;
    const int wloc = threadIdx.x >> 6;
    const int wid  = (blockIdx.x * 256 + threadIdx.x) >> 6;
    const int nw   = (gridDim.x * 256) >> 6;
    const float brl = br[lane], bcl = bc[lane];
    float s = 0.f, s2 = 0.f;

    for (int n = wid; n < NN; n += nw) {
        float xr = xn[(size_t)n * 64 + lane];   // residual
        float rx = 0.f, cx = 0.f, ras = 0.f, cas = 0.f;

        int b0 = ptr[n], e0 = ptr[n + 1];
        int i = b0;
        for (; i + 4 <= e0; i += 4) {
            int d0 = dstp[i], d1 = dstp[i + 1], d2 = dstp[i + 2], d3 = dstp[i + 3];
            float a0 = attp[i], a1 = attp[i + 1], a2 = attp[i + 2], a3 = attp[i + 3];
            float v0 = xn[(size_t)d0 * 64 + lane];
            float v1 = xn[(size_t)d1 * 64 + lane];
            float v2 = xn[(size_t)d2 * 64 + lane];
            float v3 = xn[(size_t)d3 * 64 + lane];
            rx = fmaf(v0, a0, rx); ras += a0;
            rx = fmaf(v1, a1, rx); ras += a1;
            rx = fmaf(v2, a2, rx); ras += a2;
            rx = fmaf(v3, a3, rx); ras += a3;
        }
        for (; i < e0; ++i) {
            int d = dstp[i];
            float a = attp[i];
            rx = fmaf(xn[(size_t)d * 64 + lane], a, rx);
            ras += a;
        }

        int b1 = ptr[NN + n], e1 = ptr[NN + n + 1];
        i = b1;
        for (; i + 4 <= e1; i += 4) {
            int d0 = dstp[i], d1 = dstp[i + 1], d2 = dstp[i + 2], d3 = dstp[i + 3];
            float a0 = attp[i], a1 = attp[i + 1], a2 = attp[i + 2], a3 = attp[i + 3];
            float v0 = xn[(size_t)d0 * 64 + lane];
            float v1 = xn[(size_t)d1 * 64 + lane];
            float v2 = xn[(size_t)d2 * 64 + lane];
            float v3 = xn[(size_t)d3 * 64 + lane];
            cx = fmaf(v0, a0, cx); cas += a0;
            cx = fmaf(v1, a1, cx); cas += a1;
            cx = fmaf(v2, a2, cx); cas += a2;
            cx = fmaf(v3, a3, cx); cas += a3;
        }
        for (; i < e1; ++i) {
            int d = dstp[i];
            float a = attp[i];
            cx = fmaf(xn[(size_t)d * 64 + lane], a, cx);
            cas += a;
        }

        // epilogue: dual 64x64 GEMV from LDS weights + bias·attsum + residual
        float acc = fmaf(brl, ras, fmaf(bcl, cas, xr));
#pragma unroll
        for (int k = 0; k < 64; ++k) {
            float rk = lane_bcast(rx, k);
            float ck = lane_bcast(cx, k);
            acc = fmaf(rk, sWr[k * 64 + lane], acc);
            acc = fmaf(ck, sWc[k * 64 + lane], acc);
        }
        out[(size_t)n * 64 + lane] = acc;
        s += acc;
        s2 += acc * acc;
    }

    __shared__ float ls[4][64], ls2[4][64];
    ls[wloc][lane] = s;
    ls2[wloc][lane] = s2;
    __syncthreads();
    if (threadIdx.x < 64) {
        atomicAdd(&stats[lane],      ls[0][lane] + ls[1][lane] + ls[2][lane] + ls[3][lane]);
        atomicAdd(&stats[64 + lane], ls2[0][lane] + ls2[1][lane] + ls2[2][lane] + ls2[3][lane]);
    }
}

// ------ fused output: affine+leaky -> logits = h@smW + b -> softmax ------------
__global__ __launch_bounds__(256) void out_kernel(
    const float* __restrict__ agg, const float* __restrict__ ac,
    const float* __restrict__ smW, const float* __restrict__ smb,
    float* __restrict__ out)
{
    __shared__ float sW[64 * 16];
    for (int i = threadIdx.x; i < 64 * 16; i += 256) sW[i] = smW[i];
    __syncthreads();
    const int j = threadIdx.x & 15;
    const int rloc = threadIdx.x >> 4;
    const float bj = smb[j];
    for (int row = blockIdx.x * 16 + rloc; row < NN; row += gridDim.x * 16) {
        float acc = bj;
#pragma unroll
        for (int k = 0; k < 64; ++k) {
            float v = agg[(size_t)row * 64 + k];
            v = v * ac[k] + ac[64 + k];
            v = (v > 0.f) ? v : 0.01f * v;
            acc = fmaf(v, sW[k * 16 + j], acc);
        }
        float m = acc;
#pragma unroll
        for (int off = 8; off > 0; off >>= 1) m = fmaxf(m, __shfl_xor(m, off));
        float e = expf(acc - m);
        float ssum = e;
#pragma unroll
        for (int off = 8; off > 0; off >>= 1) ssum += __shfl_xor(ssum, off);
        out[(size_t)row * 16 + j] = e / ssum;
    }
}

// ------------------------------------------------------------------------------
extern "C" void kernel_launch(void* const* d_in, const int* in_sizes, int n_in,
                              void* d_out, int out_size, void* d_ws, size_t ws_size,
                              hipStream_t stream)
{
    const float* x        = (const float*)d_in[0];
    const float* row_att  = (const float*)d_in[1];
    const float* col_att  = (const float*)d_in[2];
    const float* prelin_W = (const float*)d_in[3];
    const float* prelin_b = (const float*)d_in[4];
    const float* bn0_g    = (const float*)d_in[5];
    const float* bn0_b    = (const float*)d_in[6];
    const float* ln_g     = (const float*)d_in[7];
    const float* ln_b     = (const float*)d_in[8];
    const float* Wrv      = (const float*)d_in[9];
    const float* brv      = (const float*)d_in[10];
    const float* Wcv      = (const float*)d_in[11];
    const float* bcv      = (const float*)d_in[12];
    const float* bn_g     = (const float*)d_in[13];
    const float* bn_b     = (const float*)d_in[14];
    const float* sm_W     = (const float*)d_in[15];
    const float* sm_b     = (const float*)d_in[16];
    const int*   rowsrc   = (const int*)d_in[17];
    const int*   rowdst   = (const int*)d_in[18];
    const int*   colsrc   = (const int*)d_in[19];
    const int*   coldst   = (const int*)d_in[20];
    float* out = (float*)d_out;

    // ---- workspace layout (~200 MB) ----
    const size_t NH = (size_t)NN * 64;
    float* A = (float*)d_ws;         // stem out / layer out
    float* B = A + NH;               // xn

    char* extra = (char*)(A + 2 * NH);
    float* stats  = (float*)extra;                 extra += 3 * 128 * sizeof(float);
    float* ac     = (float*)extra;                 extra += 3 * 128 * sizeof(float);
    int*   bsum   = (int*)extra;                   extra += 512 * sizeof(int);
    int*   bpre   = (int*)extra;                   extra += 512 * sizeof(int);
    int*   ptr    = (int*)extra;                   extra += (NB + 1) * sizeof(int);
    int*   counts = (int*)extra;                   extra += NB * sizeof(int);
    int*   cursor = (int*)extra;                   extra += NB * sizeof(int);
    int*   dstp   = (int*)extra;                   extra += 2 * (size_t)EE * sizeof(int);
    float* attp   = (float*)extra;

    hipMemsetAsync(stats, 0, 3 * 128 * sizeof(float), stream);
    hipMemsetAsync(counts, 0, NB * sizeof(int), stream);

    // ---- CSR build (used by both layers) ----
    hist_kernel<<<2048, 256, 0, stream>>>(rowsrc, colsrc, counts);
    scan1_kernel<<<512, 256, 0, stream>>>(counts, bsum);
    scan2_kernel<<<1, 512, 0, stream>>>(bsum, bpre, ptr);
    scan3_kernel<<<512, 256, 0, stream>>>(counts, bpre, ptr, cursor);
    fill_kernel<<<2048, 256, 0, stream>>>(rowsrc, rowdst, row_att,
                                          colsrc, coldst, col_att,
                                          cursor, dstp, attp);

    // ---- stem ----
    stem_gemm<<<NN / 64, 256, 0, stream>>>(x, prelin_W, prelin_b, A);
    stats_kernel<<<1024, 256, 0, stream>>>(A, stats);
    finalize_bn<<<1, 64, 0, stream>>>(stats, bn0_g, bn0_b, ac);

    // ---- layer 0 ----
    ln_kernel<0><<<4096, 256, 0, stream>>>(A, ac, ln_g, ln_b, B);
    gather_gemv<<<8192, 256, 0, stream>>>(B, ptr, dstp, attp,
                                          Wrv, brv, Wcv, bcv,
                                          A, stats + 128);
    finalize_bn<<<1, 64, 0, stream>>>(stats + 128, bn_g, bn_b, ac + 128);

    // ---- layer 1 ----
    ln_kernel<1><<<4096, 256, 0, stream>>>(A, ac + 128, ln_g + 64, ln_b + 64, B);
    gather_gemv<<<8192, 256, 0, stream>>>(B, ptr, dstp, attp,
                                          Wrv + 4096, brv + 64, Wcv + 4096, bcv + 64,
                                          A, stats + 256);
    finalize_bn<<<1, 64, 0, stream>>>(stats + 256, bn_g + 64, bn_b + 64, ac + 256);

    // ---- output head ----
    out_kernel<<<2048, 256, 0, stream>>>(A, ac + 256, sm_W, sm_b, out);
}

// Round 6
// 1395.521 us; speedup vs baseline: 1.6924x; 1.3082x over previous
//
#include <hip/hip_runtime.h>
#include <math.h>

#define NN   262144      // nodes
#define CIN  200         // input channels
#define EE   2097152     // edges
#define NB   (2*NN)      // flat count/ptr sections: [row | col]
#define EPSV 1e-5f

typedef __bf16 bf16x8 __attribute__((ext_vector_type(8)));
typedef float  f32x4  __attribute__((ext_vector_type(4)));

__device__ __forceinline__ unsigned short f2bf(float f) {
    unsigned int u = __float_as_uint(f);
    unsigned int r = (u + 0x7fffu + ((u >> 16) & 1u)) >> 16;
    return (unsigned short)r;
}
__device__ __forceinline__ float bf2f(unsigned short u) {
    return __uint_as_float(((unsigned int)u) << 16);
}

// ---------------- stem GEMM: t = x @ W + b   ([N,200] @ [200,64]) --------------
__global__ __launch_bounds__(256) void stem_gemm(
    const float* __restrict__ x, const float* __restrict__ W,
    const float* __restrict__ bias, float* __restrict__ t)
{
    __shared__ float sA[40][64];
    __shared__ float sB[40][64];
    const int tid = threadIdx.x;
    const int rid = tid >> 4;
    const int cid = tid & 15;
    const int row0 = blockIdx.x * 64;

    float acc[4][4];
#pragma unroll
    for (int i = 0; i < 4; ++i)
#pragma unroll
        for (int j = 0; j < 4; ++j) acc[i][j] = 0.f;

    for (int k0 = 0; k0 < CIN; k0 += 40) {
        __syncthreads();
        for (int idx = tid; idx < 64 * 40; idx += 256) {
            int r = idx / 40, kk = idx % 40;
            sA[kk][r] = x[(size_t)(row0 + r) * CIN + k0 + kk];
        }
        for (int idx = tid; idx < 40 * 64; idx += 256) {
            int kk = idx >> 6, c = idx & 63;
            sB[kk][c] = W[(k0 + kk) * 64 + c];
        }
        __syncthreads();
#pragma unroll
        for (int kk = 0; kk < 40; ++kk) {
            const float4 a4 = *(const float4*)&sA[kk][rid * 4];
            const float4 b4 = *(const float4*)&sB[kk][cid * 4];
            acc[0][0] = fmaf(a4.x, b4.x, acc[0][0]);
            acc[0][1] = fmaf(a4.x, b4.y, acc[0][1]);
            acc[0][2] = fmaf(a4.x, b4.z, acc[0][2]);
            acc[0][3] = fmaf(a4.x, b4.w, acc[0][3]);
            acc[1][0] = fmaf(a4.y, b4.x, acc[1][0]);
            acc[1][1] = fmaf(a4.y, b4.y, acc[1][1]);
            acc[1][2] = fmaf(a4.y, b4.z, acc[1][2]);
            acc[1][3] = fmaf(a4.y, b4.w, acc[1][3]);
            acc[2][0] = fmaf(a4.z, b4.x, acc[2][0]);
            acc[2][1] = fmaf(a4.z, b4.y, acc[2][1]);
            acc[2][2] = fmaf(a4.z, b4.z, acc[2][2]);
            acc[2][3] = fmaf(a4.z, b4.w, acc[2][3]);
            acc[3][0] = fmaf(a4.w, b4.x, acc[3][0]);
            acc[3][1] = fmaf(a4.w, b4.y, acc[3][1]);
            acc[3][2] = fmaf(a4.w, b4.z, acc[3][2]);
            acc[3][3] = fmaf(a4.w, b4.w, acc[3][3]);
        }
    }
    const float4 bb = *(const float4*)&bias[cid * 4];
#pragma unroll
    for (int i = 0; i < 4; ++i) {
        float4 o;
        o.x = acc[i][0] + bb.x;
        o.y = acc[i][1] + bb.y;
        o.z = acc[i][2] + bb.z;
        o.w = acc[i][3] + bb.w;
        *(float4*)&t[(size_t)(row0 + rid * 4 + i) * 64 + cid * 4] = o;
    }
}

// ---------------- per-channel batch stats (stem only) --------------------------
__global__ __launch_bounds__(256) void stats_kernel(
    const float* __restrict__ src, float* __restrict__ stats)
{
    const int c = threadIdx.x & 63;
    const int rg = threadIdx.x >> 6;
    float s = 0.f, s2 = 0.f;
    for (int row = blockIdx.x * 4 + rg; row < NN; row += gridDim.x * 4) {
        float v = src[(size_t)row * 64 + c];
        s += v;
        s2 += v * v;
    }
    __shared__ float ls[4][64], ls2[4][64];
    ls[rg][c] = s;
    ls2[rg][c] = s2;
    __syncthreads();
    if (threadIdx.x < 64) {
        atomicAdd(&stats[c],      ls[0][c] + ls[1][c] + ls[2][c] + ls[3][c]);
        atomicAdd(&stats[64 + c], ls2[0][c] + ls2[1][c] + ls2[2][c] + ls2[3][c]);
    }
}

// fold BN into per-channel affine:  bn(v) = v*a + c
__global__ void finalize_bn(const float* __restrict__ stats,
                            const float* __restrict__ g, const float* __restrict__ b,
                            float* __restrict__ ac)
{
    int c = threadIdx.x;
    float mean = stats[c] * (1.f / NN);
    float var  = stats[64 + c] * (1.f / NN) - mean * mean;
    float rstd = rsqrtf(var + EPSV);
    float a = g[c] * rstd;
    ac[c]      = a;
    ac[64 + c] = b[c] - mean * a;
}

// ---- ln: xn = LN(leaky?(affine(u)));  writes fp32 xn + bf16 xnb ---------------
template <int RELU>
__global__ __launch_bounds__(256) void ln_kernel(
    const float* __restrict__ u, const float* __restrict__ ac,
    const float* __restrict__ lng, const float* __restrict__ lnb,
    float* __restrict__ xn, unsigned short* __restrict__ xnb)
{
    const int lane = threadIdx.x & 63;
    const int wid  = (blockIdx.x * 256 + threadIdx.x) >> 6;
    const int nw   = (gridDim.x * 256) >> 6;
    const float a  = ac[lane],  c0 = ac[64 + lane];
    const float g  = lng[lane], bl = lnb[lane];

    for (int row = wid; row < NN; row += nw) {
        float v = u[(size_t)row * 64 + lane];
        v = v * a + c0;
        if (RELU) v = (v > 0.f) ? v : 0.01f * v;
        float s = v;
#pragma unroll
        for (int off = 32; off > 0; off >>= 1) s += __shfl_xor(s, off);
        float mean = s * (1.f / 64.f);
        float d = v - mean;
        float s2 = d * d;
#pragma unroll
        for (int off = 32; off > 0; off >>= 1) s2 += __shfl_xor(s2, off);
        float rstd = rsqrtf(s2 * (1.f / 64.f) + EPSV);
        float o = d * rstd * g + bl;
        xn[(size_t)row * 64 + lane] = o;
        xnb[(size_t)row * 64 + lane] = f2bf(o);
    }
}

// ================= CSR build (graph identical for both layers) ==================
__global__ __launch_bounds__(256) void hist_kernel(
    const int* __restrict__ rowsrc, const int* __restrict__ colsrc,
    int* __restrict__ cnt)
{
    for (int i = blockIdx.x * 256 + threadIdx.x; i < EE; i += gridDim.x * 256) {
        atomicAdd(&cnt[rowsrc[i]], 1);
        atomicAdd(&cnt[NN + colsrc[i]], 1);
    }
}

__global__ __launch_bounds__(256) void scan1_kernel(
    const int* __restrict__ cnt, int* __restrict__ bsum)
{
    const int t = threadIdx.x;
    const int base = blockIdx.x * 1024 + t * 4;
    int s = cnt[base] + cnt[base + 1] + cnt[base + 2] + cnt[base + 3];
    __shared__ int sm[256];
    sm[t] = s;
    __syncthreads();
    for (int off = 1; off < 256; off <<= 1) {
        int v = (t >= off) ? sm[t - off] : 0;
        __syncthreads();
        sm[t] += v;
        __syncthreads();
    }
    if (t == 255) bsum[blockIdx.x] = sm[255];
}

__global__ __launch_bounds__(512) void scan2_kernel(
    const int* __restrict__ bsum, int* __restrict__ bpre, int* __restrict__ ptr)
{
    const int t = threadIdx.x;
    __shared__ int sm[512];
    int orig = bsum[t];
    sm[t] = orig;
    __syncthreads();
    for (int off = 1; off < 512; off <<= 1) {
        int v = (t >= off) ? sm[t - off] : 0;
        __syncthreads();
        sm[t] += v;
        __syncthreads();
    }
    bpre[t] = sm[t] - orig;
    if (t == 0) ptr[NB] = 2 * EE;
}

__global__ __launch_bounds__(256) void scan3_kernel(
    const int* __restrict__ cnt, const int* __restrict__ bpre,
    int* __restrict__ ptr, int* __restrict__ cursor)
{
    const int t = threadIdx.x;
    const int base = blockIdx.x * 1024 + t * 4;
    int c0 = cnt[base], c1 = cnt[base + 1], c2 = cnt[base + 2], c3 = cnt[base + 3];
    int tsum = c0 + c1 + c2 + c3;
    __shared__ int sm[256];
    sm[t] = tsum;
    __syncthreads();
    for (int off = 1; off < 256; off <<= 1) {
        int v = (t >= off) ? sm[t - off] : 0;
        __syncthreads();
        sm[t] += v;
        __syncthreads();
    }
    int p = bpre[blockIdx.x] + sm[t] - tsum;
    ptr[base] = p;     cursor[base] = p;     p += c0;
    ptr[base + 1] = p; cursor[base + 1] = p; p += c1;
    ptr[base + 2] = p; cursor[base + 2] = p; p += c2;
    ptr[base + 3] = p; cursor[base + 3] = p;
}

// fill: scatter packed {dst, att_bits} into CSR slots
__global__ __launch_bounds__(256) void fill_kernel(
    const int* __restrict__ rowsrc, const int* __restrict__ rowdst,
    const float* __restrict__ ratt,
    const int* __restrict__ colsrc, const int* __restrict__ coldst,
    const float* __restrict__ catt,
    int* __restrict__ cursor, int2* __restrict__ edges)
{
    for (int i = blockIdx.x * 256 + threadIdx.x; i < EE; i += gridDim.x * 256) {
        int p = atomicAdd(&cursor[rowsrc[i]], 1);
        edges[p] = make_int2(rowdst[i], __float_as_int(ratt[i]));
        int q = atomicAdd(&cursor[NN + colsrc[i]], 1);
        edges[q] = make_int2(coldst[i], __float_as_int(catt[i]));
    }
}

// ---- pure gather: rx[n] = Σ att·xnb[dst] (row), cx[n] = Σ att·xnb[dst] (col) --
__global__ __launch_bounds__(256) void gather_kernel(
    const unsigned short* __restrict__ xnb,
    const int* __restrict__ ptr, const int2* __restrict__ edges,
    unsigned short* __restrict__ rxb, unsigned short* __restrict__ cxb,
    float2* __restrict__ attsum)
{
    const int lane = threadIdx.x & 63;
    const int wid  = (blockIdx.x * 256 + threadIdx.x) >> 6;
    const int nw   = (gridDim.x * 256) >> 6;

    for (int n = wid; n < NN; n += nw) {
        float rx = 0.f, ras = 0.f, cx = 0.f, cas = 0.f;

        int b0 = ptr[n], e0 = ptr[n + 1];
        int i = b0;
        for (; i + 4 <= e0; i += 4) {
            int2 p0 = edges[i],     p1 = edges[i + 1];
            int2 p2 = edges[i + 2], p3 = edges[i + 3];
            float v0 = bf2f(xnb[(size_t)p0.x * 64 + lane]);
            float v1 = bf2f(xnb[(size_t)p1.x * 64 + lane]);
            float v2 = bf2f(xnb[(size_t)p2.x * 64 + lane]);
            float v3 = bf2f(xnb[(size_t)p3.x * 64 + lane]);
            float a0 = __int_as_float(p0.y), a1 = __int_as_float(p1.y);
            float a2 = __int_as_float(p2.y), a3 = __int_as_float(p3.y);
            rx = fmaf(v0, a0, rx); ras += a0;
            rx = fmaf(v1, a1, rx); ras += a1;
            rx = fmaf(v2, a2, rx); ras += a2;
            rx = fmaf(v3, a3, rx); ras += a3;
        }
        for (; i < e0; ++i) {
            int2 p = edges[i];
            float a = __int_as_float(p.y);
            rx = fmaf(bf2f(xnb[(size_t)p.x * 64 + lane]), a, rx);
            ras += a;
        }

        int b1 = ptr[NN + n], e1 = ptr[NN + n + 1];
        i = b1;
        for (; i + 4 <= e1; i += 4) {
            int2 p0 = edges[i],     p1 = edges[i + 1];
            int2 p2 = edges[i + 2], p3 = edges[i + 3];
            float v0 = bf2f(xnb[(size_t)p0.x * 64 + lane]);
            float v1 = bf2f(xnb[(size_t)p1.x * 64 + lane]);
            float v2 = bf2f(xnb[(size_t)p2.x * 64 + lane]);
            float v3 = bf2f(xnb[(size_t)p3.x * 64 + lane]);
            float a0 = __int_as_float(p0.y), a1 = __int_as_float(p1.y);
            float a2 = __int_as_float(p2.y), a3 = __int_as_float(p3.y);
            cx = fmaf(v0, a0, cx); cas += a0;
            cx = fmaf(v1, a1, cx); cas += a1;
            cx = fmaf(v2, a2, cx); cas += a2;
            cx = fmaf(v3, a3, cx); cas += a3;
        }
        for (; i < e1; ++i) {
            int2 p = edges[i];
            float a = __int_as_float(p.y);
            cx = fmaf(bf2f(xnb[(size_t)p.x * 64 + lane]), a, cx);
            cas += a;
        }

        rxb[(size_t)n * 64 + lane] = f2bf(rx);
        cxb[(size_t)n * 64 + lane] = f2bf(cx);
        if (lane == 0) attsum[n] = make_float2(ras, cas);
    }
}

// ---- weight pre-swizzle into MFMA B-fragment layout (bf16) --------------------
// wbuf[((((L*2+m)*2+kb)*4+t)*64+lane)*8+e] = W_L_m[(kb*32+(lane>>4)*8+e)*64 + t*16+(lane&15)]
__global__ __launch_bounds__(256) void w_convert(
    const float* __restrict__ Wrv, const float* __restrict__ Wcv,
    unsigned short* __restrict__ wbuf)
{
    int idx = blockIdx.x * 256 + threadIdx.x;   // 0..16383
    int e    = idx & 7;
    int lane = (idx >> 3) & 63;
    int t    = (idx >> 9) & 3;
    int kb   = (idx >> 11) & 1;
    int m    = (idx >> 12) & 1;
    int L    = (idx >> 13) & 1;
    const float* W = (m ? Wcv : Wrv) + L * 4096;
    float w = W[(kb * 32 + ((lane >> 4) & 3) * 8 + e) * 64 + t * 16 + (lane & 15)];
    wbuf[idx] = f2bf(w);
}

// ---- MFMA epilogue: out = xn + rx@Wr + cx@Wc + ras·br + cas·bc; fused stats ---
__global__ __launch_bounds__(256) void gemv_mfma(
    const unsigned short* __restrict__ rxb, const unsigned short* __restrict__ cxb,
    const float* __restrict__ xn, const float2* __restrict__ attsum,
    const unsigned short* __restrict__ wb16,
    const float* __restrict__ br, const float* __restrict__ bc,
    float* __restrict__ out, float* __restrict__ stats)
{
    const int lane = threadIdx.x & 63;
    const int wloc = threadIdx.x >> 6;
    const int wid  = (blockIdx.x * 256 + threadIdx.x) >> 6;
    const int nw   = (gridDim.x * 256) >> 6;
    const int lo   = lane & 15;
    const int hi   = lane >> 4;

    const bf16x8* wb = (const bf16x8*)wb16;
    bf16x8 bfr[2][2][4];
#pragma unroll
    for (int m = 0; m < 2; ++m)
#pragma unroll
        for (int kb = 0; kb < 2; ++kb)
#pragma unroll
            for (int t = 0; t < 4; ++t)
                bfr[m][kb][t] = wb[((m * 2 + kb) * 4 + t) * 64 + lane];

    float brv4[4], bcv4[4];
#pragma unroll
    for (int t = 0; t < 4; ++t) {
        brv4[t] = br[t * 16 + lo];
        bcv4[t] = bc[t * 16 + lo];
    }

    float ss[4] = {0.f, 0.f, 0.f, 0.f}, ss2[4] = {0.f, 0.f, 0.f, 0.f};
    const bf16x8* ra = (const bf16x8*)rxb;
    const bf16x8* ca = (const bf16x8*)cxb;

    for (int tile = wid; tile < NN / 16; tile += nw) {
        const int n0 = tile * 16;
        const int arow = n0 + lo;
        bf16x8 a0 = ra[arow * 8 + hi];
        bf16x8 a1 = ra[arow * 8 + 4 + hi];
        bf16x8 c0 = ca[arow * 8 + hi];
        bf16x8 c1 = ca[arow * 8 + 4 + hi];
        float2 an[4];
#pragma unroll
        for (int r = 0; r < 4; ++r) an[r] = attsum[n0 + hi * 4 + r];

#pragma unroll
        for (int t = 0; t < 4; ++t) {
            f32x4 acc = {0.f, 0.f, 0.f, 0.f};
            acc = __builtin_amdgcn_mfma_f32_16x16x32_bf16(a0, bfr[0][0][t], acc, 0, 0, 0);
            acc = __builtin_amdgcn_mfma_f32_16x16x32_bf16(a1, bfr[0][1][t], acc, 0, 0, 0);
            acc = __builtin_amdgcn_mfma_f32_16x16x32_bf16(c0, bfr[1][0][t], acc, 0, 0, 0);
            acc = __builtin_amdgcn_mfma_f32_16x16x32_bf16(c1, bfr[1][1][t], acc, 0, 0, 0);
            const int col = t * 16 + lo;
#pragma unroll
            for (int r = 0; r < 4; ++r) {
                const int n = n0 + hi * 4 + r;
                float v = acc[r] + xn[(size_t)n * 64 + col]
                        + an[r].x * brv4[t] + an[r].y * bcv4[t];
                out[(size_t)n * 64 + col] = v;
                ss[t] += v;
                ss2[t] += v * v;
            }
        }
    }

    // stats reduce: lanes sharing the same (lane&15) hold the same channels
#pragma unroll
    for (int t = 0; t < 4; ++t) {
        ss[t]  += __shfl_xor(ss[t], 16);  ss[t]  += __shfl_xor(ss[t], 32);
        ss2[t] += __shfl_xor(ss2[t], 16); ss2[t] += __shfl_xor(ss2[t], 32);
    }
    __shared__ float ls[4][64], ls2[4][64];
    if (lo == lane) {   // lanes 0..15
#pragma unroll
        for (int t = 0; t < 4; ++t) {
            ls[wloc][t * 16 + lane]  = ss[t];
            ls2[wloc][t * 16 + lane] = ss2[t];
        }
    }
    __syncthreads();
    if (threadIdx.x < 64) {
        int ch = threadIdx.x;
        atomicAdd(&stats[ch],      ls[0][ch] + ls[1][ch] + ls[2][ch] + ls[3][ch]);
        atomicAdd(&stats[64 + ch], ls2[0][ch] + ls2[1][ch] + ls2[2][ch] + ls2[3][ch]);
    }
}

// ------ fused output: affine+leaky -> logits = h@smW + b -> softmax ------------
__global__ __launch_bounds__(256) void out_kernel(
    const float* __restrict__ agg, const float* __restrict__ ac,
    const float* __restrict__ smW, const float* __restrict__ smb,
    float* __restrict__ out)
{
    __shared__ float sW[64 * 16];
    for (int i = threadIdx.x; i < 64 * 16; i += 256) sW[i] = smW[i];
    __syncthreads();
    const int j = threadIdx.x & 15;
    const int rloc = threadIdx.x >> 4;
    const float bj = smb[j];
    for (int row = blockIdx.x * 16 + rloc; row < NN; row += gridDim.x * 16) {
        float acc = bj;
#pragma unroll
        for (int k = 0; k < 64; ++k) {
            float v = agg[(size_t)row * 64 + k];
            v = v * ac[k] + ac[64 + k];
            v = (v > 0.f) ? v : 0.01f * v;
            acc = fmaf(v, sW[k * 16 + j], acc);
        }
        float m = acc;
#pragma unroll
        for (int off = 8; off > 0; off >>= 1) m = fmaxf(m, __shfl_xor(m, off));
        float e = expf(acc - m);
        float ssum = e;
#pragma unroll
        for (int off = 8; off > 0; off >>= 1) ssum += __shfl_xor(ssum, off);
        out[(size_t)row * 16 + j] = e / ssum;
    }
}

// ------------------------------------------------------------------------------
extern "C" void kernel_launch(void* const* d_in, const int* in_sizes, int n_in,
                              void* d_out, int out_size, void* d_ws, size_t ws_size,
                              hipStream_t stream)
{
    const float* x        = (const float*)d_in[0];
    const float* row_att  = (const float*)d_in[1];
    const float* col_att  = (const float*)d_in[2];
    const float* prelin_W = (const float*)d_in[3];
    const float* prelin_b = (const float*)d_in[4];
    const float* bn0_g    = (const float*)d_in[5];
    const float* bn0_b    = (const float*)d_in[6];
    const float* ln_g     = (const float*)d_in[7];
    const float* ln_b     = (const float*)d_in[8];
    const float* Wrv      = (const float*)d_in[9];
    const float* brv      = (const float*)d_in[10];
    const float* Wcv      = (const float*)d_in[11];
    const float* bcv      = (const float*)d_in[12];
    const float* bn_g     = (const float*)d_in[13];
    const float* bn_b     = (const float*)d_in[14];
    const float* sm_W     = (const float*)d_in[15];
    const float* sm_b     = (const float*)d_in[16];
    const int*   rowsrc   = (const int*)d_in[17];
    const int*   rowdst   = (const int*)d_in[18];
    const int*   colsrc   = (const int*)d_in[19];
    const int*   coldst   = (const int*)d_in[20];
    float* out = (float*)d_out;

    // ---- workspace layout (~245 MB) ----
    const size_t NH = (size_t)NN * 64;
    float* A  = (float*)d_ws;                    // stem out / layer out
    float* xn = A + NH;                          // fp32 LN output (residual)

    char* extra = (char*)(xn + NH);
    unsigned short* xnb = (unsigned short*)extra; extra += NH * sizeof(short);
    unsigned short* rxb = (unsigned short*)extra; extra += NH * sizeof(short);
    unsigned short* cxb = (unsigned short*)extra; extra += NH * sizeof(short);
    float2* attsum = (float2*)extra;              extra += (size_t)NN * sizeof(float2);
    float* stats  = (float*)extra;                extra += 3 * 128 * sizeof(float);
    float* ac     = (float*)extra;                extra += 3 * 128 * sizeof(float);
    unsigned short* wbuf = (unsigned short*)extra; extra += 16384 * sizeof(short);
    int*   bsum   = (int*)extra;                  extra += 512 * sizeof(int);
    int*   bpre   = (int*)extra;                  extra += 512 * sizeof(int);
    int*   ptr    = (int*)extra;                  extra += (NB + 1) * sizeof(int);
    int*   counts = (int*)extra;                  extra += NB * sizeof(int);
    int*   cursor = (int*)extra;                  extra += NB * sizeof(int);
    int2*  edges  = (int2*)extra;                 extra += 2 * (size_t)EE * sizeof(int2);

    hipMemsetAsync(stats, 0, 3 * 128 * sizeof(float), stream);
    hipMemsetAsync(counts, 0, NB * sizeof(int), stream);

    // ---- CSR build (used by both layers) ----
    hist_kernel<<<2048, 256, 0, stream>>>(rowsrc, colsrc, counts);
    scan1_kernel<<<512, 256, 0, stream>>>(counts, bsum);
    scan2_kernel<<<1, 512, 0, stream>>>(bsum, bpre, ptr);
    scan3_kernel<<<512, 256, 0, stream>>>(counts, bpre, ptr, cursor);
    fill_kernel<<<2048, 256, 0, stream>>>(rowsrc, rowdst, row_att,
                                          colsrc, coldst, col_att,
                                          cursor, edges);
    w_convert<<<64, 256, 0, stream>>>(Wrv, Wcv, wbuf);

    // ---- stem ----
    stem_gemm<<<NN / 64, 256, 0, stream>>>(x, prelin_W, prelin_b, A);
    stats_kernel<<<1024, 256, 0, stream>>>(A, stats);
    finalize_bn<<<1, 64, 0, stream>>>(stats, bn0_g, bn0_b, ac);

    // ---- layer 0 ----
    ln_kernel<0><<<4096, 256, 0, stream>>>(A, ac, ln_g, ln_b, xn, xnb);
    gather_kernel<<<8192, 256, 0, stream>>>(xnb, ptr, edges, rxb, cxb, attsum);
    gemv_mfma<<<1024, 256, 0, stream>>>(rxb, cxb, xn, attsum, wbuf,
                                        brv, bcv, A, stats + 128);
    finalize_bn<<<1, 64, 0, stream>>>(stats + 128, bn_g, bn_b, ac + 128);

    // ---- layer 1 ----
    ln_kernel<1><<<4096, 256, 0, stream>>>(A, ac + 128, ln_g + 64, ln_b + 64, xn, xnb);
    gather_kernel<<<8192, 256, 0, stream>>>(xnb, ptr, edges, rxb, cxb, attsum);
    gemv_mfma<<<1024, 256, 0, stream>>>(rxb, cxb, xn, attsum, wbuf + 8192,
                                        brv + 64, bcv + 64, A, stats + 256);
    finalize_bn<<<1, 64, 0, stream>>>(stats + 256, bn_g + 64, bn_b + 64, ac + 256);

    // ---- output head ----
    out_kernel<<<2048, 256, 0, stream>>>(A, ac + 256, sm_W, sm_b, out);
}